// Round 10
// baseline (207.729 us; speedup 1.0000x reference)
//
#include <hip/hip_runtime.h>

#define B_ 8
#define CIN 64
#define COUT 64
#define H_ 128
#define W_ 128
#define HW (H_*W_)
#define OFFL 26   // LDS offset stride in shorts (13 banks, odd -> conflict-free)

typedef __attribute__((ext_vector_type(8))) short short8;   // 8 bf16 (4 VGPRs)
typedef __attribute__((ext_vector_type(4))) float f32x4;    // MFMA acc

__device__ __forceinline__ short f2bf(float f) {
    unsigned u = __float_as_uint(f);
    unsigned r = (u + 0x7fffu + ((u >> 16) & 1u)) >> 16;   // RNE
    return (short)r;
}
__device__ __forceinline__ float bf2f(short s) {
    return __uint_as_float(((unsigned)(unsigned short)s) << 16);
}

// ---------- prep helper: weights -> lane-linear bf16 frags ----------
template<int NT>
__device__ __forceinline__ void prep_one(const float* __restrict__ w, short* __restrict__ o,
                                         int i, int n_used) {
    int j = i & 7, lane = (i >> 3) & 63, rest = i >> 9;
    int nt = rest % NT, dc = rest / NT, c = dc & 1, d = dc >> 1;
    int oc = nt * 16 + (lane & 15);
    int ic = c * 32 + (lane >> 4) * 8 + j;
    float v = (oc < n_used) ? w[(oc * 64 + ic) * 9 + d] : 0.f;
    o[i] = f2bf(v);
}

// ---------- K1: transpose x NCHW fp32 -> NHWC bf16, + weight prep folded in ----------
__global__ __launch_bounds__(256) void k_tr(const float* __restrict__ x,
                                            short* __restrict__ xt,
                                            const float* __restrict__ wof,
                                            const float* __restrict__ wrg,
                                            short* __restrict__ wt1,
                                            short* __restrict__ wt2) {
    int i = blockIdx.x * 256 + threadIdx.x;
    if (i < 9 * 2 * 2 * 512) prep_one<2>(wof, wt1, i, 18);
    if (i < 9 * 2 * 4 * 512) prep_one<4>(wrg, wt2, i, 64);

    __shared__ float tile[64 * 129];
    int bh = blockIdx.x;
    int bb = bh & 7, h = bh >> 3;                  // R8 mapping (A/B vs high-bit: neutral)
    const float* xp = x + (size_t)bb * (CIN * HW) + h * W_;
#pragma unroll
    for (int j = 0; j < 32; ++j) {
        int e = threadIdx.x + 256 * j;             // 8192 = 64c * 128w
        int cc = e >> 7, ww = e & 127;
        tile[cc * 129 + ww] = __builtin_nontemporal_load(xp + cc * HW + ww);
    }
    __syncthreads();
    short* op = xt + (((size_t)(bb << 7) + h) << 13);   // [b][h][w][c]
#pragma unroll
    for (int j = 0; j < 32; ++j) {
        int e = threadIdx.x + 256 * j;
        int ww = e >> 6, cc = e & 63;
        op[e] = f2bf(tile[cc * 129 + ww]);
    }
}

// ---------- sampler tap prep: 3 taps -> 12 (offset, weight) pairs ----------
__device__ __forceinline__ void prep3w(const unsigned* __restrict__ ow, int g,
                                       int w, int h, int cko,
                                       int* __restrict__ eo, float* __restrict__ wg) {
#pragma unroll
    for (int t = 0; t < 3; ++t) {
        unsigned owk = ow[g * 3 + t];
        float ox = bf2f((short)(owk & 0xffff));
        float oy = bf2f((short)(owk >> 16));
        float xs = (float)w + ox, ys = (float)h + oy;
        float x0f = floorf(xs), y0f = floorf(ys);
        float wx1 = xs - x0f, wx0 = 1.f - wx1;
        float wy1 = ys - y0f, wy0 = 1.f - wy1;
        int x0 = (int)x0f, y0 = (int)y0f;
        int x1 = x0 + 1, y1 = y0 + 1;
        int x0c = min(max(x0, 0), W_ - 1), x1c = min(max(x1, 0), W_ - 1);
        int y0c = min(max(y0, 0), H_ - 1), y1c = min(max(y1, 0), H_ - 1);
        bool vx0 = ((unsigned)x0 < W_), vx1 = ((unsigned)x1 < W_);
        bool vy0 = ((unsigned)y0 < H_), vy1 = ((unsigned)y1 < H_);
        wg[t * 4 + 0] = (vy0 && vx0) ? wy0 * wx0 : 0.f;
        wg[t * 4 + 1] = (vy0 && vx1) ? wy0 * wx1 : 0.f;
        wg[t * 4 + 2] = (vy1 && vx0) ? wy1 * wx0 : 0.f;
        wg[t * 4 + 3] = (vy1 && vx1) ? wy1 * wx1 : 0.f;
        eo[t * 4 + 0] = ((y0c * W_ + x0c) << 6) + cko;
        eo[t * 4 + 1] = ((y0c * W_ + x1c) << 6) + cko;
        eo[t * 4 + 2] = ((y1c * W_ + x0c) << 6) + cko;
        eo[t * 4 + 3] = ((y1c * W_ + x1c) << 6) + cko;
    }
}

// ---------- K2: conv1 (offsets, MFMA) + deformable sampling fused; offsets stay in LDS ----------
__global__ __launch_bounds__(1024, 4) void k_off_sample(const short* __restrict__ xt,
                                                        const short* __restrict__ wt1,
                                                        const float* __restrict__ bof,
                                                        short* __restrict__ smp) {
    __shared__ short At[6 * 130 * 64];             // 99,840 B conv input tile
    __shared__ unsigned short St[512 * OFFL];      // 26,624 B offsets (bf16 pairs)
    int blk = blockIdx.x;                          // 256 blocks
    int bb = blk & 7;                              // image
    int h0 = (blk >> 3) << 2;                      // 4 output rows h0..h0+3

    // ---- phase 1: stage 6 rows (h0-1..h0+4) x 130 px x 64 ch, branchless ----
#pragma unroll
    for (int it = 0; it < 7; ++it) {
        int s = threadIdx.x + it * 1024;           // slots: 6*130*8 = 6240
        if (s < 6240) {
            int r = s / 1040, rem = s % 1040;
            int px = rem >> 3, ck = rem & 7;
            int y = h0 - 1 + r, xx = px - 1;
            bool v = ((unsigned)y < H_) && ((unsigned)xx < W_);
            int yc = min(max(y, 0), H_ - 1), xc = min(max(xx, 0), W_ - 1);
            short8 val = *(const short8*)(xt + ((((size_t)(bb << 7) + yc) << 7) + xc) * 64 + ck * 8);
            short8 z = {0,0,0,0,0,0,0,0};
            if (!v) val = z;
            *(short8*)(&At[(r * 130 + px) * 64 + ((ck ^ (px & 7)) << 3)]) = val;
        }
    }
    __syncthreads();

    // ---- phase 2: conv1 via MFMA (N=32, 18 used), write offsets to LDS St ----
    {
        int lane = threadIdx.x & 63;
        int wave = threadIdx.x >> 6;               // 0..15
        int lr = wave >> 2;                        // local output row 0..3
        int p0 = (wave & 3) * 32;                  // 32 px per wave (2 m-tiles)
        int m = lane & 15, quad = lane >> 4;

        f32x4 acc[2][2];
#pragma unroll
        for (int nt = 0; nt < 2; ++nt) {
            int oc = nt * 16 + m;
            float bv = (oc < 18) ? bof[oc] : 0.f;
#pragma unroll
            for (int mt = 0; mt < 2; ++mt) {
                acc[mt][nt][0] = bv; acc[mt][nt][1] = bv;
                acc[mt][nt][2] = bv; acc[mt][nt][3] = bv;
            }
        }
#pragma unroll
        for (int d = 0; d < 9; ++d) {
            int dy = d / 3, dx = d % 3;
#pragma unroll
            for (int c = 0; c < 2; ++c) {
                short8 a[2];
#pragma unroll
                for (int mt = 0; mt < 2; ++mt) {
                    int px = p0 + mt * 16 + m + dx;
                    a[mt] = *(const short8*)(&At[((lr + dy) * 130 + px) * 64 + (((c * 4 + quad) ^ (px & 7)) << 3)]);
                }
#pragma unroll
                for (int nt = 0; nt < 2; ++nt) {
                    short8 b = *(const short8*)(wt1 + ((((d * 2 + c) * 2 + nt) * 64 + lane) << 3));
#pragma unroll
                    for (int mt = 0; mt < 2; ++mt)
                        acc[mt][nt] = __builtin_amdgcn_mfma_f32_16x16x32_bf16(a[mt], b, acc[mt][nt], 0, 0, 0);
                }
            }
        }
        // C/D: col(oc)=lane&15, row(px)=quad*4+reg; St and At disjoint -> no extra barrier
#pragma unroll
        for (int nt = 0; nt < 2; ++nt) {
            int oc = nt * 16 + m;
            if (oc < 18) {
#pragma unroll
                for (int mt = 0; mt < 2; ++mt) {
                    int pl = lr * 128 + p0 + mt * 16 + quad * 4;
#pragma unroll
                    for (int r = 0; r < 4; ++r)
                        St[(pl + r) * OFFL + oc] = (unsigned short)f2bf(acc[mt][nt][r]);
                }
            }
        }
    }
    __syncthreads();

    // ---- phase 3: bilinear sampling of the block's own 512 px ----
    {
        int t = threadIdx.x;
        int pxl = t >> 1;                          // 0..511
        int half = t & 1;                          // channel half (0..31 / 32..63)
        int w = pxl & 127;
        int h = h0 + (pxl >> 7);
        int pix = (bb << 14) + (h << 7) + w;
        const short* xim = xt + ((size_t)bb << 20);

        unsigned ow[9];
        const unsigned* myo = (const unsigned*)&St[pxl * OFFL];
#pragma unroll
        for (int k = 0; k < 9; ++k) ow[k] = myo[k];

#pragma unroll
        for (int cq = 0; cq < 4; ++cq) {
            int cko = ((half << 2) + cq) << 3;     // channel-chunk byte..element offset
            float acc[8];
#pragma unroll
            for (int i = 0; i < 8; ++i) acc[i] = 0.f;
#pragma unroll
            for (int g = 0; g < 3; ++g) {
                int eo[12]; float wg[12];
                prep3w(ow, g, w, h, cko, eo, wg);
                short8 v[12];
#pragma unroll
                for (int n = 0; n < 12; ++n) v[n] = *(const short8*)(xim + eo[n]);
#pragma unroll
                for (int n = 0; n < 12; ++n) {
                    float wv = wg[n];
#pragma unroll
                    for (int i = 0; i < 8; ++i) acc[i] += wv * bf2f(v[n][i]);
                }
            }
            short8 o;
#pragma unroll
            for (int i = 0; i < 8; ++i) o[i] = f2bf(acc[i]);
            *(short8*)(smp + (size_t)pix * 64 + cko) = o;
        }
    }
}

// ---------- K3: conv2 via MFMA (out NCHW fp32, nt stores) ----------
__global__ __launch_bounds__(1024, 4) void k_conv2(const short* __restrict__ smp,
                                                   const short* __restrict__ wt2,
                                                   const float* __restrict__ brg,
                                                   float* __restrict__ out) {
    __shared__ short At[6 * 130 * 64];             // 99,840 B
    int blk = blockIdx.x;                          // 256 blocks
    int bb = blk & 7;
    int h0 = (blk >> 3) << 2;

#pragma unroll
    for (int it = 0; it < 7; ++it) {
        int s = threadIdx.x + it * 1024;
        if (s < 6240) {
            int r = s / 1040, rem = s % 1040;
            int px = rem >> 3, ck = rem & 7;
            int y = h0 - 1 + r, xx = px - 1;
            bool v = ((unsigned)y < H_) && ((unsigned)xx < W_);
            int yc = min(max(y, 0), H_ - 1), xc = min(max(xx, 0), W_ - 1);
            short8 val = *(const short8*)(smp + ((((size_t)(bb << 7) + yc) << 7) + xc) * 64 + ck * 8);
            short8 z = {0,0,0,0,0,0,0,0};
            if (!v) val = z;
            *(short8*)(&At[(r * 130 + px) * 64 + ((ck ^ (px & 7)) << 3)]) = val;
        }
    }
    __syncthreads();

    int lane = threadIdx.x & 63;
    int wave = threadIdx.x >> 6;
    int lr = wave >> 2;
    int p0 = (wave & 3) * 32;
    int m = lane & 15, quad = lane >> 4;

    f32x4 acc[2][4];
#pragma unroll
    for (int nt = 0; nt < 4; ++nt) {
        float bv = brg[nt * 16 + m];
#pragma unroll
        for (int mt = 0; mt < 2; ++mt) {
            acc[mt][nt][0] = bv; acc[mt][nt][1] = bv;
            acc[mt][nt][2] = bv; acc[mt][nt][3] = bv;
        }
    }
#pragma unroll
    for (int d = 0; d < 9; ++d) {
        int dy = d / 3, dx = d % 3;
#pragma unroll
        for (int c = 0; c < 2; ++c) {
            short8 a[2];
#pragma unroll
            for (int mt = 0; mt < 2; ++mt) {
                int px = p0 + mt * 16 + m + dx;
                a[mt] = *(const short8*)(&At[((lr + dy) * 130 + px) * 64 + (((c * 4 + quad) ^ (px & 7)) << 3)]);
            }
#pragma unroll
            for (int nt = 0; nt < 4; ++nt) {
                short8 b = *(const short8*)(wt2 + ((((d * 2 + c) * 4 + nt) * 64 + lane) << 3));
#pragma unroll
                for (int mt = 0; mt < 2; ++mt)
                    acc[mt][nt] = __builtin_amdgcn_mfma_f32_16x16x32_bf16(a[mt], b, acc[mt][nt], 0, 0, 0);
            }
        }
    }
#pragma unroll
    for (int nt = 0; nt < 4; ++nt) {
        int oc = nt * 16 + m;
#pragma unroll
        for (int mt = 0; mt < 2; ++mt) {
            int wpix = p0 + mt * 16 + quad * 4;
            __builtin_nontemporal_store(acc[mt][nt],
                (f32x4*)(out + (((size_t)(bb * 64 + oc)) << 14) + ((h0 + lr) << 7) + wpix));
        }
    }
}

extern "C" void kernel_launch(void* const* d_in, const int* in_sizes, int n_in,
                              void* d_out, int out_size, void* d_ws, size_t ws_size,
                              hipStream_t stream) {
    const float* x   = (const float*)d_in[0];
    const float* wof = (const float*)d_in[1];
    const float* bof = (const float*)d_in[2];
    const float* wrg = (const float*)d_in[3];
    const float* brg = (const float*)d_in[4];
    float* out = (float*)d_out;

    char* ws = (char*)d_ws;
    short* xt   = (short*)ws;                                   // 16,777,216 B
    short* smp  = (short*)(ws + 16777216);                      // 16,777,216 B
    short* wt1  = (short*)(ws + 2 * 16777216);                  //     36,864 B
    short* wt2  = (short*)(ws + 2 * 16777216 + 36864);          //     73,728 B

    k_tr        <<<dim3(B_ * H_),     256,  0, stream>>>(x, xt, wof, wrg, wt1, wt2);
    k_off_sample<<<dim3(B_ * H_ / 4), 1024, 0, stream>>>(xt, wt1, bof, smp);
    k_conv2     <<<dim3(B_ * H_ / 4), 1024, 0, stream>>>(smp, wt2, brg, out);
}

// Round 11
// 147.030 us; speedup vs baseline: 1.4128x; 1.4128x over previous
//
#include <hip/hip_runtime.h>

#define B_ 8
#define CIN 64
#define COUT 64
#define H_ 128
#define W_ 128
#define HW (H_*W_)
#define OFFP 24   // shorts per pixel in offb (9 taps * 2 + pad -> 48B, 16B aligned)

typedef __attribute__((ext_vector_type(8))) short short8;   // 8 bf16 (4 VGPRs)
typedef __attribute__((ext_vector_type(4))) float f32x4;    // MFMA acc

__device__ __forceinline__ short f2bf(float f) {
    unsigned u = __float_as_uint(f);
    unsigned r = (u + 0x7fffu + ((u >> 16) & 1u)) >> 16;   // RNE
    return (short)r;
}
__device__ __forceinline__ float bf2f(short s) {
    return __uint_as_float(((unsigned)(unsigned short)s) << 16);
}

// ---------- prep helper: weights -> lane-linear bf16 frags ----------
template<int NT>
__device__ __forceinline__ void prep_one(const float* __restrict__ w, short* __restrict__ o,
                                         int i, int n_used) {
    int j = i & 7, lane = (i >> 3) & 63, rest = i >> 9;
    int nt = rest % NT, dc = rest / NT, c = dc & 1, d = dc >> 1;
    int oc = nt * 16 + (lane & 15);
    int ic = c * 32 + (lane >> 4) * 8 + j;
    float v = (oc < n_used) ? w[(oc * 64 + ic) * 9 + d] : 0.f;
    o[i] = f2bf(v);
}

// ---------- transpose x NCHW fp32 -> NHWC bf16, + weight prep folded in ----------
__global__ __launch_bounds__(256) void k_tr(const float* __restrict__ x,
                                            short* __restrict__ xt,
                                            const float* __restrict__ wof,
                                            const float* __restrict__ wrg,
                                            short* __restrict__ wt1,
                                            short* __restrict__ wt2) {
    int i = blockIdx.x * 256 + threadIdx.x;
    if (i < 9 * 2 * 2 * 512) prep_one<2>(wof, wt1, i, 18);
    if (i < 9 * 2 * 4 * 512) prep_one<4>(wrg, wt2, i, 64);

    __shared__ float tile[64 * 129];
    int bh = blockIdx.x;
    int bb = bh & 7, h = bh >> 3;
    const float* xp = x + (size_t)bb * (CIN * HW) + h * W_;
#pragma unroll
    for (int j = 0; j < 32; ++j) {
        int e = threadIdx.x + 256 * j;             // 8192 = 64c * 128w
        int cc = e >> 7, ww = e & 127;
        tile[cc * 129 + ww] = __builtin_nontemporal_load(xp + cc * HW + ww);
    }
    __syncthreads();
    short* op = xt + (((size_t)(bb << 7) + h) << 13);   // [b][h][w][c]
#pragma unroll
    for (int j = 0; j < 32; ++j) {
        int e = threadIdx.x + 256 * j;
        int ww = e >> 6, cc = e & 63;
        op[e] = f2bf(tile[cc * 129 + ww]);
    }
}

// ---------- conv via MFMA: block = 4 output rows (1024 thr, 99.8 KB LDS) ----------
template<int NT, bool TO_OFF>
__global__ __launch_bounds__(1024, 4) void k_conv(const short* __restrict__ src,
                                                  const short* __restrict__ wt,
                                                  const float* __restrict__ bias,
                                                  short* __restrict__ outb,
                                                  float* __restrict__ outf) {
    __shared__ short At[6 * 130 * 64];             // 99,840 B, XOR-swizzled chunks
    int blk = blockIdx.x;                          // 256 blocks
    int bb = blk & 7;                              // image
    int h0 = (blk >> 3) << 2;                      // 4 output rows h0..h0+3

#pragma unroll
    for (int it = 0; it < 7; ++it) {
        int s = threadIdx.x + it * 1024;           // slots: 6*130*8 = 6240
        if (s < 6240) {
            int r = s / 1040, rem = s % 1040;
            int px = rem >> 3, ck = rem & 7;
            int y = h0 - 1 + r, xx = px - 1;
            bool v = ((unsigned)y < H_) && ((unsigned)xx < W_);
            int yc = min(max(y, 0), H_ - 1), xc = min(max(xx, 0), W_ - 1);
            short8 val = *(const short8*)(src + ((((size_t)(bb << 7) + yc) << 7) + xc) * 64 + ck * 8);
            short8 z = {0,0,0,0,0,0,0,0};
            if (!v) val = z;
            *(short8*)(&At[(r * 130 + px) * 64 + ((ck ^ (px & 7)) << 3)]) = val;
        }
    }
    __syncthreads();

    int lane = threadIdx.x & 63;
    int wave = threadIdx.x >> 6;                   // 0..15
    int lr = wave >> 2;                            // local output row 0..3
    int p0 = (wave & 3) * 32;                      // 32 px per wave (2 m-tiles)
    int m = lane & 15, quad = lane >> 4;

    f32x4 acc[2][NT];
#pragma unroll
    for (int nt = 0; nt < NT; ++nt) {
        int oc = nt * 16 + m;
        float bv = (!TO_OFF || oc < 18) ? bias[oc] : 0.f;
#pragma unroll
        for (int mt = 0; mt < 2; ++mt) {
            acc[mt][nt][0] = bv; acc[mt][nt][1] = bv;
            acc[mt][nt][2] = bv; acc[mt][nt][3] = bv;
        }
    }

#pragma unroll
    for (int d = 0; d < 9; ++d) {
        int dy = d / 3, dx = d % 3;
#pragma unroll
        for (int c = 0; c < 2; ++c) {
            short8 a[2];
#pragma unroll
            for (int mt = 0; mt < 2; ++mt) {
                int px = p0 + mt * 16 + m + dx;
                a[mt] = *(const short8*)(&At[((lr + dy) * 130 + px) * 64 + (((c * 4 + quad) ^ (px & 7)) << 3)]);
            }
#pragma unroll
            for (int nt = 0; nt < NT; ++nt) {
                short8 b = *(const short8*)(wt + ((((d * 2 + c) * NT + nt) * 64 + lane) << 3));
#pragma unroll
                for (int mt = 0; mt < 2; ++mt)
                    acc[mt][nt] = __builtin_amdgcn_mfma_f32_16x16x32_bf16(a[mt], b, acc[mt][nt], 0, 0, 0);
            }
        }
    }

    if (TO_OFF) {
        __syncthreads();
        unsigned short* St = (unsigned short*)At;  // [512 px][OFFP]
#pragma unroll
        for (int nt = 0; nt < NT; ++nt) {
            int oc = nt * 16 + m;
            if (oc < 20) {
#pragma unroll
                for (int mt = 0; mt < 2; ++mt) {
                    int pl = lr * 128 + p0 + mt * 16 + quad * 4;
#pragma unroll
                    for (int r = 0; r < 4; ++r)
                        St[(pl + r) * OFFP + oc] = (unsigned short)f2bf(acc[mt][nt][r]);
                }
            }
        }
        __syncthreads();
        const unsigned* Sd = (const unsigned*)St;            // 6144 dwords
        unsigned* Od = (unsigned*)(outb + ((size_t)((bb << 14) + (h0 << 7))) * OFFP);
#pragma unroll
        for (int j = 0; j < 6; ++j)
            Od[threadIdx.x + 1024 * j] = Sd[threadIdx.x + 1024 * j];
    } else {
#pragma unroll
        for (int nt = 0; nt < NT; ++nt) {
            int oc = nt * 16 + m;
#pragma unroll
            for (int mt = 0; mt < 2; ++mt) {
                int wpix = p0 + mt * 16 + quad * 4;
                __builtin_nontemporal_store(acc[mt][nt],
                    (f32x4*)(outf + (((size_t)(bb * 64 + oc)) << 14) + ((h0 + lr) << 7) + wpix));
            }
        }
    }
}

// ---------- sampler helpers ----------
__device__ __forceinline__ void prep3(const unsigned* __restrict__ myo, int g,
                                      int w, int h, int cko,
                                      int* __restrict__ eo, float* __restrict__ wg) {
#pragma unroll
    for (int t = 0; t < 3; ++t) {
        unsigned owk = myo[g * 3 + t];
        float ox = bf2f((short)(owk & 0xffff));
        float oy = bf2f((short)(owk >> 16));
        float xs = (float)w + ox, ys = (float)h + oy;
        float x0f = floorf(xs), y0f = floorf(ys);
        float wx1 = xs - x0f, wx0 = 1.f - wx1;
        float wy1 = ys - y0f, wy0 = 1.f - wy1;
        int x0 = (int)x0f, y0 = (int)y0f;
        int x1 = x0 + 1, y1 = y0 + 1;
        int x0c = min(max(x0, 0), W_ - 1), x1c = min(max(x1, 0), W_ - 1);
        int y0c = min(max(y0, 0), H_ - 1), y1c = min(max(y1, 0), H_ - 1);
        bool vx0 = ((unsigned)x0 < W_), vx1 = ((unsigned)x1 < W_);
        bool vy0 = ((unsigned)y0 < H_), vy1 = ((unsigned)y1 < H_);
        wg[t * 4 + 0] = (vy0 && vx0) ? wy0 * wx0 : 0.f;
        wg[t * 4 + 1] = (vy0 && vx1) ? wy0 * wx1 : 0.f;
        wg[t * 4 + 2] = (vy1 && vx0) ? wy1 * wx0 : 0.f;
        wg[t * 4 + 3] = (vy1 && vx1) ? wy1 * wx1 : 0.f;
        eo[t * 4 + 0] = ((y0c * W_ + x0c) << 6) + cko;
        eo[t * 4 + 1] = ((y0c * W_ + x1c) << 6) + cko;
        eo[t * 4 + 2] = ((y1c * W_ + x0c) << 6) + cko;
        eo[t * 4 + 3] = ((y1c * W_ + x1c) << 6) + cko;
    }
}

// ---------- deformable bilinear sample: 8x4 tile, LDS offsets, full-36 prefetch ----------
__global__ __launch_bounds__(256, 2) void k_sample(const short* __restrict__ xt,
                                                   const short* __restrict__ offb,
                                                   short* __restrict__ smp) {
    __shared__ unsigned sow[4 * 96];             // 4 rows x 8 px x 12 dwords
    int blk = blockIdx.x;                        // 4096 blocks
    int bb = blk & 7;                            // image
    int tile = blk >> 3;
    int tw = tile & 15, th = tile >> 4;

    // cooperative offset staging (stream-once -> nontemporal loads)
    {
        int rowid = threadIdx.x >> 6, rl = threadIdx.x & 63;
        const unsigned* srcp = (const unsigned*)(offb +
            ((size_t)((bb << 14) + (((th << 2) + rowid) << 7) + (tw << 3))) * OFFP);
        sow[rowid * 96 + rl] = __builtin_nontemporal_load(srcp + rl);
        if (rl < 32) sow[rowid * 96 + 64 + rl] = __builtin_nontemporal_load(srcp + 64 + rl);
    }
    __syncthreads();

    int lp = threadIdx.x >> 3;                   // local pixel 0..31 (8w x 4h)
    int ck = threadIdx.x & 7;                    // channel chunk
    int w = (tw << 3) + (lp & 7);
    int h = (th << 2) + (lp >> 3);
    int pix = (bb << 14) + (h << 7) + w;
    const short* xim = xt + ((size_t)bb << 20);
    int cko = ck * 8;
    const unsigned* myo = &sow[(lp >> 3) * 96 + (lp & 7) * 12];

    int eo[12];
    float wgtA[12], wgtB[12], wgtC[12];
    short8 vA[12], vB[12], vC[12];
    float acc[8];
#pragma unroll
    for (int i = 0; i < 8; ++i) acc[i] = 0.f;

    // issue ALL 36 gathers before any consumption (max MLP)
    prep3(myo, 0, w, h, cko, eo, wgtA);
#pragma unroll
    for (int n = 0; n < 12; ++n) vA[n] = *(const short8*)(xim + eo[n]);
    prep3(myo, 1, w, h, cko, eo, wgtB);
#pragma unroll
    for (int n = 0; n < 12; ++n) vB[n] = *(const short8*)(xim + eo[n]);
    prep3(myo, 2, w, h, cko, eo, wgtC);
#pragma unroll
    for (int n = 0; n < 12; ++n) vC[n] = *(const short8*)(xim + eo[n]);

#pragma unroll
    for (int n = 0; n < 12; ++n) {
        float wv = wgtA[n];
#pragma unroll
        for (int i = 0; i < 8; ++i) acc[i] += wv * bf2f(vA[n][i]);
    }
#pragma unroll
    for (int n = 0; n < 12; ++n) {
        float wv = wgtB[n];
#pragma unroll
        for (int i = 0; i < 8; ++i) acc[i] += wv * bf2f(vB[n][i]);
    }
#pragma unroll
    for (int n = 0; n < 12; ++n) {
        float wv = wgtC[n];
#pragma unroll
        for (int i = 0; i < 8; ++i) acc[i] += wv * bf2f(vC[n][i]);
    }

    short8 o;
#pragma unroll
    for (int i = 0; i < 8; ++i) o[i] = f2bf(acc[i]);
    *(short8*)(smp + (size_t)pix * 64 + cko) = o;
}

extern "C" void kernel_launch(void* const* d_in, const int* in_sizes, int n_in,
                              void* d_out, int out_size, void* d_ws, size_t ws_size,
                              hipStream_t stream) {
    const float* x   = (const float*)d_in[0];
    const float* wof = (const float*)d_in[1];
    const float* bof = (const float*)d_in[2];
    const float* wrg = (const float*)d_in[3];
    const float* brg = (const float*)d_in[4];
    float* out = (float*)d_out;

    char* ws = (char*)d_ws;
    short* xt   = (short*)ws;                                   // 16,777,216 B
    short* smp  = (short*)(ws + 16777216);                      // 16,777,216 B
    short* offb = (short*)(ws + 2 * 16777216);                  //  6,291,456 B
    short* wt1  = (short*)(ws + 2 * 16777216 + 6291456);        //     36,864 B
    short* wt2  = (short*)(ws + 2 * 16777216 + 6291456 + 36864);//     73,728 B

    k_tr   <<<dim3(B_ * H_), 256, 0, stream>>>(x, xt, wof, wrg, wt1, wt2);
    k_conv<2, true>  <<<dim3(B_ * H_ / 4), 1024, 0, stream>>>(xt, wt1, bof, offb, nullptr);
    k_sample<<<dim3((B_ * HW * 8) / 256), 256, 0, stream>>>(xt, offb, smp);
    k_conv<4, false> <<<dim3(B_ * H_ / 4), 1024, 0, stream>>>(smp, wt2, brg, nullptr, out);
}